// Round 2
// baseline (445.406 us; speedup 1.0000x reference)
//
#include <hip/hip_runtime.h>
#include <math.h>

#define DIM 1280
#define NDIM 8
#define CHUNKS 5   // 5 chunks * 64 lanes * 4 floats = 1280

__device__ __forceinline__ void load_x(const float* __restrict__ x, int t, int lane,
                                       float4 xv[CHUNKS]) {
    const float4* xp = (const float4*)(x + (size_t)t * DIM);
    #pragma unroll
    for (int c = 0; c < CHUNKS; ++c) xv[c] = xp[c * 64 + lane];
}

__device__ __forceinline__ void compute_store(const float4 xv[CHUNKS],
                                              const float4 w[CHUNKS][NDIM],
                                              float T, float bd, int p3,
                                              int lane, int t, int* __restrict__ out) {
    float acc[NDIM];
    #pragma unroll
    for (int k = 0; k < NDIM; ++k) acc[k] = 0.0f;

    #pragma unroll
    for (int c = 0; c < CHUNKS; ++c) {
        #pragma unroll
        for (int k = 0; k < NDIM; ++k) {
            acc[k] = fmaf(xv[c].x, w[c][k].x, acc[k]);
            acc[k] = fmaf(xv[c].y, w[c][k].y, acc[k]);
            acc[k] = fmaf(xv[c].z, w[c][k].z, acc[k]);
            acc[k] = fmaf(xv[c].w, w[c][k].w, acc[k]);
        }
    }

    // Dimension-exchange reduction: 7 shuffles instead of 48.
    // After 3 exchange steps lane l holds dim d(l) = (l&1)<<2 | (l&2) | (l>>2)&1
    // summed over its 8-lane oct; 3 more xor steps complete the 64-lane sum.
    const int bit0 = lane & 1, bit1 = lane & 2, bit2 = lane & 4;
    float r4[4];
    #pragma unroll
    for (int j = 0; j < 4; ++j) {
        float send = bit0 ? acc[j] : acc[j + 4];
        float recv = __shfl_xor(send, 1, 64);
        r4[j] = (bit0 ? acc[j + 4] : acc[j]) + recv;
    }
    float r2[2];
    #pragma unroll
    for (int j = 0; j < 2; ++j) {
        float send = bit1 ? r4[j] : r4[j + 2];
        float recv = __shfl_xor(send, 2, 64);
        r2[j] = (bit1 ? r4[j + 2] : r4[j]) + recv;
    }
    float r1;
    {
        float send = bit2 ? r2[0] : r2[1];
        float recv = __shfl_xor(send, 4, 64);
        r1 = (bit2 ? r2[1] : r2[0]) + recv;
    }
    r1 += __shfl_xor(r1, 8, 64);
    r1 += __shfl_xor(r1, 16, 64);
    r1 += __shfl_xor(r1, 32, 64);

    // Quantize this lane's dim, scale by 3^d, then base-3 pack across the oct.
    float h = r1 + bd;
    int dig = 1 + (h > T ? 1 : 0) - (h < -T ? 1 : 0);  // {0,1,2}
    int mu = dig * p3;
    mu += __shfl_xor(mu, 1, 64);
    mu += __shfl_xor(mu, 2, 64);
    mu += __shfl_xor(mu, 4, 64);
    if (lane == 0) out[t] = mu;
}

__global__ __launch_bounds__(256, 2)
void fsq_kernel(const float* __restrict__ x, const float* __restrict__ W,
                const float* __restrict__ b, int* __restrict__ out, int n_tok) {
    const int lane    = threadIdx.x & 63;
    const int wave    = (int)((blockIdx.x * blockDim.x + threadIdx.x) >> 6);
    const int n_waves = (int)((gridDim.x * blockDim.x) >> 6);

    // digit = +1 iff tanh(h)*SCALE > 0.5  <=>  h > atanh(0.5/SCALE); tanh monotone,
    // exact 0.5 rounds to 0 under round-half-even, matched by strict >.
    const float T = (float)atanh(0.5 / 0.9990000128746033);

    // This lane's output dim after the exchange reduction, its bias and 3^d.
    const int d = ((lane & 1) << 2) | (lane & 2) | ((lane >> 2) & 1);
    const float bd = b[d];
    int p3 = 1;
    for (int i = 0; i < d; ++i) p3 *= 3;

    // W fragments in registers, amortized over the token loop (160 VGPRs).
    float4 w[CHUNKS][NDIM];
    #pragma unroll
    for (int c = 0; c < CHUNKS; ++c) {
        #pragma unroll
        for (int k = 0; k < NDIM; ++k) {
            w[c][k] = *(const float4*)(W + k * DIM + c * 256 + lane * 4);
        }
    }

    int t = wave;
    if (t >= n_tok) return;

    // Register double-buffer: prefetch token t+n_waves while computing t.
    float4 xa[CHUNKS], xb[CHUNKS];
    load_x(x, t, lane, xa);
    while (true) {
        const int t1 = t + n_waves;
        if (t1 < n_tok) load_x(x, t1, lane, xb);
        compute_store(xa, w, T, bd, p3, lane, t, out);
        if (t1 >= n_tok) break;

        const int t2 = t1 + n_waves;
        if (t2 < n_tok) load_x(x, t2, lane, xa);
        compute_store(xb, w, T, bd, p3, lane, t1, out);
        if (t2 >= n_tok) break;
        t = t2;
    }
}

extern "C" void kernel_launch(void* const* d_in, const int* in_sizes, int n_in,
                              void* d_out, int out_size, void* d_ws, size_t ws_size,
                              hipStream_t stream) {
    const float* x = (const float*)d_in[0];   // (B*T, 1280) fp32
    const float* W = (const float*)d_in[1];   // (8, 1280) fp32
    const float* b = (const float*)d_in[2];   // (8,) fp32
    int* out = (int*)d_out;                   // (B*T,) int32

    const int n_tok = in_sizes[0] / DIM;      // 65536
    const int blocks = 2048;                  // 8192 waves -> 8 tokens/wave
    fsq_kernel<<<blocks, 256, 0, stream>>>(x, W, b, out, n_tok);
}